// Round 2
// baseline (430.444 us; speedup 1.0000x reference)
//
#include <hip/hip_runtime.h>
#include <hip/hip_bf16.h>

// QuantLinearAWQ: out[T,N] = x[T,K] @ ((q - z) * s)[K,N] + bias[N]
// T=32, K=4096, N=11008, group=128. qweight int32 (180 MB) dominates traffic.
// R1 -> R2: latency-bound (VALU 14%, HBM 11%, occ 13%). Fix: 4 cols/thread
// (int4 16B loads, halves LDS-read per FMA), KCHUNK=128=1 group (no g-loop),
// 128-thr blocks -> 704 blocks for balance.

#define TOKENS   32
#define KDIM     4096
#define NDIM     11008
#define GS       128
#define KSPLIT   32
#define KCHUNK   128               // == GS: one quant group per block
#define XS_STRIDE 36               // 144 B rows: 16B-aligned for ds_read_b128
#define BLOCK    128
#define COLS     4                 // columns per thread (int4 weight loads)

__global__ __launch_bounds__(256) void awq_init_kernel(
    const float* __restrict__ bias, float* __restrict__ out)
{
    // grid (43, 32): 43*256 == 11008 exactly
    const int n = blockIdx.x * 256 + threadIdx.x;
    out[blockIdx.y * NDIM + n] = bias[n];
}

__global__ __launch_bounds__(BLOCK) void awq_gemm_kernel(
    const float* __restrict__ x,
    const int*   __restrict__ qw,
    const int*   __restrict__ qz,
    const float* __restrict__ sc,
    float*       __restrict__ out)
{
    __shared__ float xs[KCHUNK * XS_STRIDE];   // 18432 B

    const int tid = threadIdx.x;
    const int kc0 = blockIdx.y * KCHUNK;

    // Stage x[0:32][kc0:kc0+128] transposed: xs[k_local][t].
    // Global side coalesced (128 lanes x 4B contiguous per t).
    #pragma unroll
    for (int t = 0; t < TOKENS; ++t) {
        xs[tid * XS_STRIDE + t] = x[t * KDIM + kc0 + tid];
    }
    __syncthreads();

    const int n0 = blockIdx.x * (BLOCK * COLS) + tid * COLS;
    if (n0 >= NDIM) return;   // tail block (bx=21): upper 64 threads idle

    // KCHUNK == GS: exactly one quant group -> one scale/zero fetch.
    // (q-8)-(z-8) == q-z : recentering cancels. w = fma(q, s, -z*s).
    const int grp = blockIdx.y;
    const float4 s4 = *(const float4*)&sc[(size_t)grp * NDIM + n0];
    const int4   z4 = *(const int4*)  &qz[(size_t)grp * NDIM + n0];
    const float nzs0 = -(float)z4.x * s4.x;
    const float nzs1 = -(float)z4.y * s4.y;
    const float nzs2 = -(float)z4.z * s4.z;
    const float nzs3 = -(float)z4.w * s4.w;

    float acc0[TOKENS], acc1[TOKENS], acc2[TOKENS], acc3[TOKENS];
    #pragma unroll
    for (int t = 0; t < TOKENS; ++t) {
        acc0[t] = 0.f; acc1[t] = 0.f; acc2[t] = 0.f; acc3[t] = 0.f;
    }

    const int4* qp = (const int4*)(qw + (size_t)kc0 * NDIM + n0);

    #pragma unroll 4
    for (int k = 0; k < KCHUNK; ++k) {
        const int4 q = qp[(size_t)k * (NDIM / 4)];   // 16B/lane coalesced
        const float w0 = fmaf((float)q.x, s4.x, nzs0);
        const float w1 = fmaf((float)q.y, s4.y, nzs1);
        const float w2 = fmaf((float)q.z, s4.z, nzs2);
        const float w3 = fmaf((float)q.w, s4.w, nzs3);

        const float4* xp = (const float4*)&xs[k * XS_STRIDE];
        #pragma unroll
        for (int t4 = 0; t4 < 8; ++t4) {
            const float4 xv = xp[t4];   // broadcast ds_read_b128 (conflict-free)
            acc0[t4*4+0] = fmaf(w0, xv.x, acc0[t4*4+0]);
            acc1[t4*4+0] = fmaf(w1, xv.x, acc1[t4*4+0]);
            acc2[t4*4+0] = fmaf(w2, xv.x, acc2[t4*4+0]);
            acc3[t4*4+0] = fmaf(w3, xv.x, acc3[t4*4+0]);
            acc0[t4*4+1] = fmaf(w0, xv.y, acc0[t4*4+1]);
            acc1[t4*4+1] = fmaf(w1, xv.y, acc1[t4*4+1]);
            acc2[t4*4+1] = fmaf(w2, xv.y, acc2[t4*4+1]);
            acc3[t4*4+1] = fmaf(w3, xv.y, acc3[t4*4+1]);
            acc0[t4*4+2] = fmaf(w0, xv.z, acc0[t4*4+2]);
            acc1[t4*4+2] = fmaf(w1, xv.z, acc1[t4*4+2]);
            acc2[t4*4+2] = fmaf(w2, xv.z, acc2[t4*4+2]);
            acc3[t4*4+2] = fmaf(w3, xv.z, acc3[t4*4+2]);
            acc0[t4*4+3] = fmaf(w0, xv.w, acc0[t4*4+3]);
            acc1[t4*4+3] = fmaf(w1, xv.w, acc1[t4*4+3]);
            acc2[t4*4+3] = fmaf(w2, xv.w, acc2[t4*4+3]);
            acc3[t4*4+3] = fmaf(w3, xv.w, acc3[t4*4+3]);
        }
    }

    // K-split combine: HW fp32 atomics (global_atomic_add_f32), ~46 MB total.
    float* op = out + n0;
    #pragma unroll
    for (int t = 0; t < TOKENS; ++t) {
        unsafeAtomicAdd(op + (size_t)t * NDIM + 0, acc0[t]);
        unsafeAtomicAdd(op + (size_t)t * NDIM + 1, acc1[t]);
        unsafeAtomicAdd(op + (size_t)t * NDIM + 2, acc2[t]);
        unsafeAtomicAdd(op + (size_t)t * NDIM + 3, acc3[t]);
    }
}

extern "C" void kernel_launch(void* const* d_in, const int* in_sizes, int n_in,
                              void* d_out, int out_size, void* d_ws, size_t ws_size,
                              hipStream_t stream) {
    const float* x    = (const float*)d_in[0];
    const int*   qw   = (const int*)  d_in[1];
    const int*   qz   = (const int*)  d_in[2];
    const float* sc   = (const float*)d_in[3];
    const float* bias = (const float*)d_in[4];
    float* out = (float*)d_out;

    // 1) out = broadcast(bias)   (d_out is poisoned 0xAA before every launch)
    awq_init_kernel<<<dim3(NDIM / 256, TOKENS), 256, 0, stream>>>(bias, out);
    // 2) out += x @ W_deq, K split 32 ways (1 group per block)
    awq_gemm_kernel<<<dim3((NDIM + BLOCK * COLS - 1) / (BLOCK * COLS), KSPLIT),
                      BLOCK, 0, stream>>>(x, qw, qz, sc, out);
}

// Round 3
// 291.737 us; speedup vs baseline: 1.4755x; 1.4755x over previous
//
#include <hip/hip_runtime.h>
#include <hip/hip_bf16.h>

// QuantLinearAWQ: out[T,N] = x[T,K] @ ((q - z) * s)[K,N] + bias[N]
// T=32, K=4096, N=11008, group=128.
// R2 -> R3: both prior rounds were ATOMIC-pipe bound (38-47 G atomics/s in
// both) and LDS-broadcast capped (8KB/wave/k-iter over ~85B/cyc return bus).
// Fix: (a) partials to ws + reduce kernel, zero atomics; (b) x transposed to
// xT[k][t] so the 32 token values are wave-uniform contiguous 128B -> scalar
// s_load into SGPRs, v_fmac vgpr,sgpr,vgpr -> zero LDS in hot loop.

#define TOKENS   32
#define KDIM     4096
#define NDIM     11008
#define GS       128
#define KSPLIT   32
#define KCHUNK   128               // == GS: one quant group per k-block
#define BLOCK    128
#define COLS     2                 // 43*BLOCK*COLS == 11008 exactly, no tail
#define NB       (NDIM / (BLOCK * COLS))   // 43

// ---------- x transpose: xT[k][t] = x[t][k]  (512 KB, ~2us) ----------
__global__ __launch_bounds__(256) void awq_xpose_kernel(
    const float* __restrict__ x, float* __restrict__ xT)
{
    __shared__ float tile[64 * 33];        // stride 33: conflict-free
    const int tid = threadIdx.x;
    const int k0  = blockIdx.x * 64;       // 64 blocks cover K=4096
    const int kk  = tid & 63;
    const int tq  = tid >> 6;              // 0..3
    #pragma unroll
    for (int i = 0; i < 8; ++i) {
        const int t = tq + 4 * i;          // 0..31
        tile[kk * 33 + t] = x[t * KDIM + k0 + kk];   // coalesced read
    }
    __syncthreads();
    #pragma unroll
    for (int i = 0; i < 8; ++i) {
        const int o  = tid + 256 * i;      // 0..2047
        const int t  = o & 31;
        const int k  = o >> 5;
        xT[(k0 + k) * TOKENS + t] = tile[k * 33 + t]; // coalesced write
    }
}

// ---------- bias init (atomic-fallback path only) ----------
__global__ __launch_bounds__(256) void awq_init_kernel(
    const float* __restrict__ bias, float* __restrict__ out)
{
    const int n = blockIdx.x * 256 + threadIdx.x;   // grid (43, 32)
    out[blockIdx.y * NDIM + n] = bias[n];
}

// ---------- main fused dequant-GEMM ----------
template<bool ATOMIC>
__global__ __launch_bounds__(BLOCK) void awq_gemm_kernel(
    const float* __restrict__ xT,     // [K][T]
    const int*   __restrict__ qw,
    const int*   __restrict__ qz,
    const float* __restrict__ sc,
    float*       __restrict__ dst)    // partials [KSPLIT][T][N] or out [T][N]
{
    const int tid = threadIdx.x;
    const int kc0 = blockIdx.y * KCHUNK;
    const int n0  = blockIdx.x * (BLOCK * COLS) + tid * COLS;

    // KCHUNK == GS: one quant group. (q-8)-(z-8) == q-z; w = fma(q,s,-z*s).
    const int grp = blockIdx.y;
    const float2 s2 = *(const float2*)&sc[(size_t)grp * NDIM + n0];
    const int2   z2 = *(const int2*)  &qz[(size_t)grp * NDIM + n0];
    const float nzs0 = -(float)z2.x * s2.x;
    const float nzs1 = -(float)z2.y * s2.y;

    float acc0[TOKENS], acc1[TOKENS];
    #pragma unroll
    for (int t = 0; t < TOKENS; ++t) { acc0[t] = 0.f; acc1[t] = 0.f; }

    const int2* qp = (const int2*)(qw + (size_t)kc0 * NDIM + n0);

    #pragma unroll 2
    for (int k = 0; k < KCHUNK; ++k) {
        const int2 q = qp[(size_t)k * (NDIM / 2)];    // 8B/lane coalesced
        const float w0 = fmaf((float)q.x, s2.x, nzs0);
        const float w1 = fmaf((float)q.y, s2.y, nzs1);

        // Wave-uniform address -> compiler scalarizes to s_load_dwordx4;
        // x values live in SGPRs, fmac reads sgpr operand (1/instr legal).
        const float4* xk = (const float4*)(xT + (size_t)(kc0 + k) * TOKENS);
        #pragma unroll
        for (int j = 0; j < 8; ++j) {
            const float4 xv = xk[j];
            acc0[j*4+0] = fmaf(w0, xv.x, acc0[j*4+0]);
            acc1[j*4+0] = fmaf(w1, xv.x, acc1[j*4+0]);
            acc0[j*4+1] = fmaf(w0, xv.y, acc0[j*4+1]);
            acc1[j*4+1] = fmaf(w1, xv.y, acc1[j*4+1]);
            acc0[j*4+2] = fmaf(w0, xv.z, acc0[j*4+2]);
            acc1[j*4+2] = fmaf(w1, xv.z, acc1[j*4+2]);
            acc0[j*4+3] = fmaf(w0, xv.w, acc0[j*4+3]);
            acc1[j*4+3] = fmaf(w1, xv.w, acc1[j*4+3]);
        }
    }

    if (ATOMIC) {
        float* op = dst + n0;
        #pragma unroll
        for (int t = 0; t < TOKENS; ++t) {
            unsafeAtomicAdd(op + (size_t)t * NDIM + 0, acc0[t]);
            unsafeAtomicAdd(op + (size_t)t * NDIM + 1, acc1[t]);
        }
    } else {
        // plain coalesced float2 stores: partial[split][t][n]
        float* pp = dst + ((size_t)blockIdx.y * TOKENS) * NDIM + n0;
        #pragma unroll
        for (int t = 0; t < TOKENS; ++t) {
            *(float2*)(pp + (size_t)t * NDIM) = make_float2(acc0[t], acc1[t]);
        }
    }
}

// ---------- reduce KSPLIT partials + bias ----------
__global__ __launch_bounds__(256) void awq_reduce_kernel(
    const float* __restrict__ part,   // [KSPLIT][T][N]
    const float* __restrict__ bias,
    float*       __restrict__ out)    // [T][N]
{
    const int o = blockIdx.x * 256 + threadIdx.x;   // float4 index, 88064 total
    const int t = o / (NDIM / 4);
    const int c = o - t * (NDIM / 4);
    const float4* p4 = (const float4*)part;
    float4 sum = ((const float4*)bias)[c];
    #pragma unroll
    for (int s = 0; s < KSPLIT; ++s) {
        const float4 v = p4[(size_t)(s * TOKENS + t) * (NDIM / 4) + c];
        sum.x += v.x; sum.y += v.y; sum.z += v.z; sum.w += v.w;
    }
    ((float4*)out)[o] = sum;
}

extern "C" void kernel_launch(void* const* d_in, const int* in_sizes, int n_in,
                              void* d_out, int out_size, void* d_ws, size_t ws_size,
                              hipStream_t stream) {
    const float* x    = (const float*)d_in[0];
    const int*   qw   = (const int*)  d_in[1];
    const int*   qz   = (const int*)  d_in[2];
    const float* sc   = (const float*)d_in[3];
    const float* bias = (const float*)d_in[4];
    float* out = (float*)d_out;

    const size_t xt_bytes   = (size_t)KDIM * TOKENS * sizeof(float);     // 512 KB
    const size_t part_bytes = (size_t)KSPLIT * TOKENS * NDIM * sizeof(float); // 45 MB
    float* xT   = (float*)d_ws;
    float* part = (float*)((char*)d_ws + xt_bytes);

    awq_xpose_kernel<<<KDIM / 64, 256, 0, stream>>>(x, xT);

    if (ws_size >= xt_bytes + part_bytes) {
        awq_gemm_kernel<false><<<dim3(NB, KSPLIT), BLOCK, 0, stream>>>(
            xT, qw, qz, sc, part);
        awq_reduce_kernel<<<(TOKENS * NDIM / 4) / 256, 256, 0, stream>>>(
            part, bias, out);
    } else {
        // fallback: atomic combine (slower, but fits any ws)
        awq_init_kernel<<<dim3(NDIM / 256, TOKENS), 256, 0, stream>>>(bias, out);
        awq_gemm_kernel<true><<<dim3(NB, KSPLIT), BLOCK, 0, stream>>>(
            xT, qw, qz, sc, out);
    }
}

// Round 4
// 279.192 us; speedup vs baseline: 1.5417x; 1.0449x over previous
//
#include <hip/hip_runtime.h>
#include <hip/hip_bf16.h>

// QuantLinearAWQ: out[T,N] = x[T,K] @ ((q - z) * s)[K,N] + bias[N]
// T=32, K=4096, N=11008, group=128.
// R3 -> R4: VALU-broadcast architecture is structurally capped (VALUBusy
// <20% across 3 rounds; per-weight cost = 32 VALU FMAs). Switch to MFMA
// (16x16x32 bf16): per-weight cost drops to ~5 VALU (dequant+pack), matrix
// pipe does the 2.88 GF. Kernel becomes pure weight streaming:
// floor ~15-29us (91MB L3-warm / 180MB cold). No atomics, no LDS.

#define TOKENS   32
#define KDIM     4096
#define NDIM     11008
#define GS       128
#define KSPLIT   32
#define KCHUNK   128               // == GS: one quant group per k-block
#define BLOCK    256               // 4 waves
#define WAVE_N   64                // 4 n-tiles of 16 per wave
#define BLOCK_N  256               // 43 * 256 == 11008 exactly

typedef __attribute__((ext_vector_type(8))) short short8;   // 8 x bf16
typedef __attribute__((ext_vector_type(4))) float floatx4;  // MFMA C/D

__device__ __forceinline__ short f2bf(float f) {
    // round-to-nearest-even bf16 (inputs finite)
    unsigned u = __builtin_bit_cast(unsigned, f);
    u += 0x7fffu + ((u >> 16) & 1u);
    return (short)(u >> 16);
}

// ---------- x fp32 -> bf16 (256 KB, L1/L2-resident during gemm) ----------
__global__ __launch_bounds__(256) void awq_cvt_kernel(
    const float* __restrict__ x, unsigned short* __restrict__ xb)
{
    const int i = blockIdx.x * 256 + threadIdx.x;      // grid 128: 32768 float4s
    const float4 v = ((const float4*)x)[i];
    ushort4 o;
    o.x = (unsigned short)f2bf(v.x);
    o.y = (unsigned short)f2bf(v.y);
    o.z = (unsigned short)f2bf(v.z);
    o.w = (unsigned short)f2bf(v.w);
    ((ushort4*)xb)[i] = o;
}

// ---------- bias init (atomic-fallback path only) ----------
__global__ __launch_bounds__(256) void awq_init_kernel(
    const float* __restrict__ bias, float* __restrict__ out)
{
    const int n = blockIdx.x * 256 + threadIdx.x;      // grid (43, 32)
    out[blockIdx.y * NDIM + n] = bias[n];
}

// ---------- MFMA dequant-GEMM ----------
// A-frag (verified): A[m=lane&15][k=quad*8+j]; C/D: col=lane&15, row=quad*4+reg.
// B-frag symmetric to A: B[k=quad*8+j][n=lane&15].
template<bool ATOMIC>
__global__ __launch_bounds__(BLOCK) void awq_gemm_mfma(
    const unsigned short* __restrict__ xb,   // [T][K] bf16
    const int*   __restrict__ qw,            // [K][N] codes
    const int*   __restrict__ qz,            // [K/GS][N]
    const float* __restrict__ sc,            // [K/GS][N]
    float*       __restrict__ dst)           // part [KSPLIT][T][N] or out [T][N]
{
    const int tid  = threadIdx.x;
    const int lane = tid & 63;
    const int wv   = tid >> 6;               // 0..3
    const int col  = lane & 15;
    const int quad = lane >> 4;              // 0..3
    const int g    = blockIdx.y;             // group index == k-split index
    const int kc0  = g * KCHUNK;
    const int nb   = blockIdx.x * BLOCK_N + wv * WAVE_N;

    // per-n-tile scale / fused zero: w = q*s + (-z*s)  ((q-8)-(z-8) == q-z)
    float s[4], nzs[4];
    #pragma unroll
    for (int nt = 0; nt < 4; ++nt) {
        const int n  = nb + nt * 16 + col;
        const float sv = sc[(size_t)g * NDIM + n];
        const int   zv = qz[(size_t)g * NDIM + n];
        s[nt] = sv; nzs[nt] = -(float)zv * sv;
    }

    floatx4 acc[4][2];
    #pragma unroll
    for (int nt = 0; nt < 4; ++nt) {
        acc[nt][0] = (floatx4){0.f, 0.f, 0.f, 0.f};
        acc[nt][1] = (floatx4){0.f, 0.f, 0.f, 0.f};
    }

    const int* qp = qw + (size_t)(kc0 + quad * 8) * NDIM + nb + col;
    const unsigned short* xr0 = xb + (size_t)col * KDIM + kc0 + quad * 8;
    const unsigned short* xr1 = xr0 + 16 * KDIM;

    #pragma unroll 2
    for (int ks = 0; ks < KCHUNK / 32; ++ks) {   // 4 k-steps of 32
        // issue all 32 weight loads first (latency overlap)
        int q[4][8];
        #pragma unroll
        for (int nt = 0; nt < 4; ++nt)
            #pragma unroll
            for (int j = 0; j < 8; ++j)
                q[nt][j] = qp[(ks * 32 + j) * NDIM + nt * 16];

        const short8 a0 = *(const short8*)(xr0 + ks * 32);   // tokens 0-15
        const short8 a1 = *(const short8*)(xr1 + ks * 32);   // tokens 16-31

        #pragma unroll
        for (int nt = 0; nt < 4; ++nt) {
            short8 b;
            #pragma unroll
            for (int j = 0; j < 8; ++j)
                b[j] = f2bf(fmaf((float)q[nt][j], s[nt], nzs[nt]));
            acc[nt][0] = __builtin_amdgcn_mfma_f32_16x16x32_bf16(a0, b, acc[nt][0], 0, 0, 0);
            acc[nt][1] = __builtin_amdgcn_mfma_f32_16x16x32_bf16(a1, b, acc[nt][1], 0, 0, 0);
        }
    }

    // C/D: token = h*16 + quad*4 + r, n = nb + nt*16 + col (64B-coalesced)
    if (ATOMIC) {
        #pragma unroll
        for (int nt = 0; nt < 4; ++nt)
            #pragma unroll
            for (int h = 0; h < 2; ++h) {
                float* pp = dst + (size_t)(h * 16 + quad * 4) * NDIM + nb + nt * 16 + col;
                #pragma unroll
                for (int r = 0; r < 4; ++r)
                    unsafeAtomicAdd(pp + (size_t)r * NDIM, acc[nt][h][r]);
            }
    } else {
        float* pbase = dst + (size_t)g * TOKENS * NDIM;
        #pragma unroll
        for (int nt = 0; nt < 4; ++nt)
            #pragma unroll
            for (int h = 0; h < 2; ++h) {
                float* pp = pbase + (size_t)(h * 16 + quad * 4) * NDIM + nb + nt * 16 + col;
                #pragma unroll
                for (int r = 0; r < 4; ++r)
                    pp[(size_t)r * NDIM] = acc[nt][h][r];
            }
    }
}

// ---------- reduce KSPLIT partials + bias ----------
__global__ __launch_bounds__(256) void awq_reduce_kernel(
    const float* __restrict__ part,   // [KSPLIT][T][N]
    const float* __restrict__ bias,
    float*       __restrict__ out)    // [T][N]
{
    const int o = blockIdx.x * 256 + threadIdx.x;   // float4 idx, 88064 total
    const int t = o / (NDIM / 4);
    const int c = o - t * (NDIM / 4);
    const float4* p4 = (const float4*)part;
    float4 sum = ((const float4*)bias)[c];
    #pragma unroll 8
    for (int s = 0; s < KSPLIT; ++s) {
        const float4 v = p4[(size_t)(s * TOKENS + t) * (NDIM / 4) + c];
        sum.x += v.x; sum.y += v.y; sum.z += v.z; sum.w += v.w;
    }
    ((float4*)out)[o] = sum;
}

extern "C" void kernel_launch(void* const* d_in, const int* in_sizes, int n_in,
                              void* d_out, int out_size, void* d_ws, size_t ws_size,
                              hipStream_t stream) {
    const float* x    = (const float*)d_in[0];
    const int*   qw   = (const int*)  d_in[1];
    const int*   qz   = (const int*)  d_in[2];
    const float* sc   = (const float*)d_in[3];
    const float* bias = (const float*)d_in[4];
    float* out = (float*)d_out;

    const size_t xb_bytes   = 512 * 1024;  // 256 KB used, padded
    const size_t part_bytes = (size_t)KSPLIT * TOKENS * NDIM * sizeof(float); // 45 MB
    unsigned short* xb = (unsigned short*)d_ws;
    float* part = (float*)((char*)d_ws + xb_bytes);

    awq_cvt_kernel<<<(TOKENS * KDIM / 4) / 256, 256, 0, stream>>>(x, xb);

    if (ws_size >= xb_bytes + part_bytes) {
        awq_gemm_mfma<false><<<dim3(NDIM / BLOCK_N, KSPLIT), BLOCK, 0, stream>>>(
            xb, qw, qz, sc, part);
        awq_reduce_kernel<<<(TOKENS * NDIM / 4) / 256, 256, 0, stream>>>(
            part, bias, out);
    } else {
        awq_init_kernel<<<dim3(NDIM / 256, TOKENS), 256, 0, stream>>>(bias, out);
        awq_gemm_mfma<true><<<dim3(NDIM / BLOCK_N, KSPLIT), BLOCK, 0, stream>>>(
            xb, qw, qz, sc, out);
    }
}